// Round 7
// baseline (8140.083 us; speedup 1.0000x reference)
//
#include <hip/hip_runtime.h>
#include <hip/hip_bf16.h>
#include <stdint.h>
#include <math.h>

#define B   64
#define T   1000
#define INP 64
#define HID 512
#define ACT 2

#define NSLICE 2                    // ring of 2: one partner block per group
#define MROWS  2                    // batch rows per block
#define NGROUP (B / MROWS)          // 32 row-groups
#define NBLOCKS (NGROUP * NSLICE)   // 64 worker slots
#define NLAUNCH 256                 // launched blocks (claim surplus exits)
#define WORK_PER_XCD 8              // 4 groups x 2 slices per XCD
#define COLS   (HID / NSLICE)       // 256 cols per block
#define HLPAD  544                  // row stride (shorts): bank shift 16/row

#define FAST_GUARD 256              // fast re-poll budget (sticky demotion)
#define SAFE_GUARD (1 << 18)        // MALL-poll budget (fail fast, no hang)

typedef __attribute__((ext_vector_type(8))) short short8;     // 8 bf16
typedef __attribute__((ext_vector_type(4))) float floatx4;    // MFMA C/D
typedef __attribute__((ext_vector_type(4))) uint32_t uint32x4;

// ---------------------------------------------------------------------------
// L2 fast-path primitives (same-XCD L2 shared by all CUs on the XCD):
//   load : sc0 = bypass L1, read the XCD's L2
//   store: plain = write-through L1 into own-XCD L2
// Producers ALWAYS dual-store (h_fast plain + h_safe agent/MALL); consumers
// fast-poll with bounded budget and wave-uniform sticky fallback to MALL
// (round-3 lesson: the fast path is flaky for some waves in some runs).
// ---------------------------------------------------------------------------
__device__ __forceinline__ uint32x4 l2_load128(const void* p) {
  uint32x4 v;
  asm volatile("global_load_dwordx4 %0, %1, off sc0\n\t"
               "s_waitcnt vmcnt(0)"
               : "=v"(v) : "v"(p) : "memory");
  return v;
}
__device__ __forceinline__ uint32x4 l2_load128_nowait(const void* p) {
  uint32x4 v;
  asm volatile("global_load_dwordx4 %0, %1, off sc0"
               : "=v"(v) : "v"(p) : "memory");
  return v;
}
__device__ __forceinline__ void l2_store64(uint64_t* p, uint64_t v) {
  asm volatile("global_store_dwordx2 %0, %1, off"
               :: "v"(p), "v"(v) : "memory");
}
__device__ __forceinline__ int get_xcc_id() {
  int x;
  asm volatile("s_getreg_b32 %0, hwreg(HW_REG_XCC_ID)" : "=s"(x));
  return x & 7;
}
__device__ __forceinline__ int tags_ok(uint32x4 v, uint32_t want) {
  return (((v[0] ^ want) | (v[1] ^ want) | (v[2] ^ want) | (v[3] ^ want)) &
          0xFFFFu) == 0;
}

// ctrl layout (u32): [0..7] per-XCD claim counters, [8] claimed, [9] arrivals,
// [10] mode flag (0=undecided, 1=fallback layout, 2=XCD layout)
#define CTRL_WORDS 16

// ---------------------------------------------------------------------------
// Exchange word layout: [parity][group][col] -> u64 = (row1 << 32) | row0,
// each u32 = (bf16 bits << 16) | (step_tag & 0xFFFF); h_t carries tag t+1.
// ---------------------------------------------------------------------------
__global__ __launch_bounds__(256) void init_kernel(
    const float* __restrict__ hn, uint64_t* __restrict__ h_fast,
    uint64_t* __restrict__ h_safe, uint32_t* __restrict__ ctrl) {
  if (blockIdx.x == 0 && threadIdx.x < CTRL_WORDS) ctrl[threadIdx.x] = 0;
  const int i   = blockIdx.x * 256 + threadIdx.x;  // 0 .. NGROUP*HID-1
  const int g   = i >> 9;                          // / HID
  const int col = i & (HID - 1);
  __hip_bfloat16 b0 = __float2bfloat16(hn[(2 * g) * HID + col]);
  __hip_bfloat16 b1 = __float2bfloat16(hn[(2 * g + 1) * HID + col]);
  const uint32_t w0 = ((uint32_t)*reinterpret_cast<unsigned short*>(&b0)) << 16;
  const uint32_t w1 = ((uint32_t)*reinterpret_cast<unsigned short*>(&b1)) << 16;
  const uint64_t v  = (uint64_t)w0 | ((uint64_t)w1 << 32);  // tag 0
  const size_t p1 = (size_t)NGROUP * HID + i;               // parity 1
  h_fast[p1] = v;
  h_safe[p1] = v;
  h_fast[i] = 0x0000FFFE0000FFFEull;  // parity 0: non-matching tag
  h_safe[i] = 0x0000FFFE0000FFFEull;
}

// ---------------------------------------------------------------------------
// K1: xproj[b,t,:] = inp[b,t,:] @ W_ih  -> rnn slab (overwritten by h later)
// ---------------------------------------------------------------------------
__global__ __launch_bounds__(256) void xproj_kernel(
    const float* __restrict__ inp, const float* __restrict__ W_ih,
    float* __restrict__ rnn) {
  __shared__ float xin[16 * INP];
  const int tid = threadIdx.x;
  const long r0 = (long)blockIdx.x * 16;

  const float4* inp4 = (const float4*)(inp + r0 * INP);
  ((float4*)xin)[tid] = inp4[tid];
  __syncthreads();

  const int j = tid, j2 = tid + 256;
  float acc0[16], acc1[16];
#pragma unroll
  for (int r = 0; r < 16; ++r) { acc0[r] = 0.f; acc1[r] = 0.f; }

  for (int i = 0; i < INP; ++i) {
    const float w0 = W_ih[i * HID + j];
    const float w1 = W_ih[i * HID + j2];
#pragma unroll
    for (int r = 0; r < 16; ++r) {
      const float x = xin[r * INP + i];
      acc0[r] = fmaf(x, w0, acc0[r]);
      acc1[r] = fmaf(x, w1, acc1[r]);
    }
  }
#pragma unroll
  for (int r = 0; r < 16; ++r) {
    rnn[(r0 + r) * HID + j]  = acc0[r];
    rnn[(r0 + r) * HID + j2] = acc1[r];
  }
}

// ---------------------------------------------------------------------------
// K2: recurrence, ring-of-2, split-K. Phase A = MFMA over OWN 256 K-cols
// (no exchange dependency) overlapping the remote prefetch's L2 RTT; then
// tag-check (near-zero wait), stage, barrier, Phase B over remote K-cols.
// xp reads / rnn writes batched at 16-step granularity (R4-proven) so the
// per-step barrier vmcnt(0) drain stays cheap.
// ---------------------------------------------------------------------------
__global__ __launch_bounds__(512, 2) void rnn_mfma(
    const float* __restrict__ W_hh, float* __restrict__ rnn,
    float* __restrict__ hn_out, uint64_t* __restrict__ h_fast,
    uint64_t* __restrict__ h_safe, uint32_t* __restrict__ ctrl) {
  __shared__ __align__(16) unsigned short hl[2][MROWS][HLPAD];
  __shared__ float xbuf[8][16][2][32];    // [wave][step][row][col32] 32 KB
  __shared__ float rstage[16][2][COLS];   // [step][row][col256]      32 KB
  __shared__ int sh_g, sh_s, sh_work, sh_mode;

  const int tid = threadIdx.x;

  // ---- claim a (group, slice) slot on this block's physical XCD
  if (tid == 0) {
    uint32_t* cnt      = ctrl;          // [8]
    uint32_t* claimed  = ctrl + 8;
    uint32_t* arrivals = ctrl + 9;
    uint32_t* flag     = ctrl + 10;
    const int xcc = get_xcc_id();
    const int slot = (int)__hip_atomic_fetch_add(
        &cnt[xcc], 1u, __ATOMIC_RELAXED, __HIP_MEMORY_SCOPE_AGENT);
    int work = 0, g = 0, s = 0;
    if (slot < WORK_PER_XCD) {          // groups [4*xcc,4*xcc+4) x 2 slices
      g = xcc * 4 + (slot >> 1);
      s = slot & 1;
      work = 1;
      __hip_atomic_fetch_add(claimed, 1u, __ATOMIC_RELEASE,
                             __HIP_MEMORY_SCOPE_AGENT);
    }
    const int arr = (int)__hip_atomic_fetch_add(
        arrivals, 1u, __ATOMIC_ACQ_REL, __HIP_MEMORY_SCOPE_AGENT);
    if (arr == NLAUNCH - 1) {           // last arriver decides, once, for all
      const uint32_t c = __hip_atomic_load(claimed, __ATOMIC_ACQUIRE,
                                           __HIP_MEMORY_SCOPE_AGENT);
      __hip_atomic_store(flag, (c == NBLOCKS) ? 2u : 1u, __ATOMIC_RELEASE,
                         __HIP_MEMORY_SCOPE_AGENT);
    }
    uint32_t f = 0; int guard = 0;
    do {
      f = __hip_atomic_load(flag, __ATOMIC_ACQUIRE, __HIP_MEMORY_SCOPE_AGENT);
    } while (f == 0 && ++guard < (1 << 20));
    if (f != 2) {                       // globally-consistent fallback layout
      work = (blockIdx.x < NBLOCKS);
      g = blockIdx.x & (NGROUP - 1);
      s = blockIdx.x >> 5;
    }
    sh_g = g; sh_s = s; sh_work = work; sh_mode = (f == 2);
  }
  __syncthreads();
  if (!sh_work) return;                 // block-uniform: no further barriers

  const int g = __builtin_amdgcn_readfirstlane(sh_g);
  const int s = __builtin_amdgcn_readfirstlane(sh_s);
  int fastmode = __builtin_amdgcn_readfirstlane(sh_mode);  // sticky per wave

  const int lane = tid & 63;
  const int w    = tid >> 6;              // wave 0..7
  const int r0   = g * MROWS;
  const int sp   = s ^ 1;                 // partner slice
  const int n_base = s * COLS + w * 32;   // wave covers 32 cols, 2 n-tiles

  const int lm = lane & 15;               // MFMA m/n lane index
  const int lq = lane >> 4;               // quad 0..3 -> k-subchunk
  const int cca = n_base + lm;            // n-tile 0 column
  const int ccb = cca + 16;               // n-tile 1 column

  // ---- one-time: W_hh column slices -> bf16 B-frags (2 tiles per wave)
  short8 bfA[16], bfB[16];
#pragma unroll
  for (int kt = 0; kt < 16; ++kt) {
    short8 fa, fb;
#pragma unroll
    for (int i = 0; i < 8; ++i) {
      const int k = kt * 32 + lq * 8 + i;
      __hip_bfloat16 ha = __float2bfloat16(W_hh[k * HID + cca]);
      __hip_bfloat16 hb = __float2bfloat16(W_hh[k * HID + ccb]);
      fa[i] = *reinterpret_cast<short*>(&ha);
      fb[i] = *reinterpret_cast<short*>(&hb);
    }
    bfA[kt] = fa;
    bfB[kt] = fb;
  }

  const int  arow = lm & 1;               // A row duplication (M=2 real rows)
  const bool prod = (lq == 0);            // producer lanes (hold C rows 0,1)
  const bool need = prod;                 // poll lanes: 16/wave x 2 words
  const size_t exbase = (size_t)g * HID;
  const int widx = sp * COLS + w * 32 + lm * 2;  // this lane's remote words

  // ---- xp register pipeline: steps [0,16): reg i <-> step i
  const int xrow = (lane >> 5) & 1, xcol = lane & 31;
  float xreg[16];
#pragma unroll
  for (int i = 0; i < 16; ++i)
    xreg[i] = rnn[((long)(r0 + xrow) * T + i) * HID + n_base + xcol];

  // ---- t==0: stage ALL 512 words of h_{-1} (parity 1, tag 0)
  if (lq < 2) {
    const int i0 = w * 32 + lq * 16 + lm;            // 0..255
    const int w0 = 2 * i0;
    const size_t idx0 = (size_t)NGROUP * HID + exbase + w0;
    uint32x4 v = {0, 0, 0, 0};
    if (fastmode) {
      int it = 0;
      for (;;) {
        v = l2_load128(h_fast + idx0);
        if (tags_ok(v, 0u)) break;
        if (++it > FAST_GUARD) { fastmode = 0; break; }
      }
    }
    if (!fastmode) {
      int gd = 0;
      for (;;) {
        const uint64_t a = __hip_atomic_load(h_safe + idx0, __ATOMIC_RELAXED,
                                             __HIP_MEMORY_SCOPE_AGENT);
        const uint64_t b = __hip_atomic_load(h_safe + idx0 + 1,
                                             __ATOMIC_RELAXED,
                                             __HIP_MEMORY_SCOPE_AGENT);
        v[0] = (uint32_t)a; v[1] = (uint32_t)(a >> 32);
        v[2] = (uint32_t)b; v[3] = (uint32_t)(b >> 32);
        if (tags_ok(v, 0u)) break;
        if (++gd > SAFE_GUARD) break;
      }
    }
    *reinterpret_cast<uint32_t*>(&hl[1][0][w0]) =
        (v[0] >> 16) | (v[2] & 0xFFFF0000u);
    *reinterpret_cast<uint32_t*>(&hl[1][1][w0]) =
        (v[1] >> 16) | (v[3] & 0xFFFF0000u);
  }
  __syncthreads();

  uint32x4 vpre = {0, 0, 0, 0};

  for (int t = 0; t < T; ++t) {
    const int p  = (t + 1) & 1;           // parity holding h_{t-1}
    const int tb = t & 15;
    const uint32_t want = (uint32_t)t & 0xFFFFu;
    const size_t ridx = (size_t)p * NGROUP * HID + exbase + widx;

    // ---- issue remote prefetch (no wait): RTT hides under Phase A
    if (fastmode && t) {
      if (need) vpre = l2_load128_nowait(h_fast + ridx);
    }

    // ---- Phase A: own-K MFMA (8 chunks), no exchange dependency
    floatx4 cA[4], cB[4];
#pragma unroll
    for (int j = 0; j < 4; ++j) {
      cA[j] = floatx4{0.f, 0.f, 0.f, 0.f};
      cB[j] = floatx4{0.f, 0.f, 0.f, 0.f};
    }
#pragma unroll
    for (int j = 0; j < 8; ++j) {
      const int kt = s * 8 + j;
      short8 a = *(const short8*)(&hl[p][arow][kt * 32 + lq * 8]);
      cA[j & 3] = __builtin_amdgcn_mfma_f32_16x16x32_bf16(a, bfA[kt], cA[j & 3], 0, 0, 0);
      cB[j & 3] = __builtin_amdgcn_mfma_f32_16x16x32_bf16(a, bfB[kt], cB[j & 3], 0, 0, 0);
    }

    // ---- collect prefetch, check tags, re-poll if stale, stage remote
    if (t) {
      asm volatile("s_waitcnt vmcnt(0)" ::: "memory");
      __builtin_amdgcn_sched_barrier(0);
      if (fastmode) {
        int ok = need ? tags_ok(vpre, want) : 1;
        int it = 0;
        while (!__all(ok)) {
          if (need && !ok) {
            vpre = l2_load128(h_fast + ridx);
            ok = tags_ok(vpre, want);
          }
          if (++it > FAST_GUARD) { fastmode = 0; break; }  // wave-uniform
        }
      }
      if (!fastmode) {                    // MALL path (demoted or fallback)
        if (need) {
          int gd = 0;
          for (;;) {
            const uint64_t a = __hip_atomic_load(h_safe + ridx,
                                                 __ATOMIC_RELAXED,
                                                 __HIP_MEMORY_SCOPE_AGENT);
            const uint64_t b = __hip_atomic_load(h_safe + ridx + 1,
                                                 __ATOMIC_RELAXED,
                                                 __HIP_MEMORY_SCOPE_AGENT);
            vpre[0] = (uint32_t)a; vpre[1] = (uint32_t)(a >> 32);
            vpre[2] = (uint32_t)b; vpre[3] = (uint32_t)(b >> 32);
            if (tags_ok(vpre, want)) break;
            if (++gd > SAFE_GUARD) break;
          }
        }
      }
      if (need) {
        *reinterpret_cast<uint32_t*>(&hl[p][0][widx]) =
            (vpre[0] >> 16) | (vpre[2] & 0xFFFF0000u);
        *reinterpret_cast<uint32_t*>(&hl[p][1][widx]) =
            (vpre[1] >> 16) | (vpre[3] & 0xFFFF0000u);
      }
    }
    __syncthreads();                      // remote staged by all waves

    // ---- Phase B: remote-K MFMA (8 chunks)
#pragma unroll
    for (int j = 0; j < 8; ++j) {
      const int kt = sp * 8 + j;
      short8 a = *(const short8*)(&hl[p][arow][kt * 32 + lq * 8]);
      cA[j & 3] = __builtin_amdgcn_mfma_f32_16x16x32_bf16(a, bfA[kt], cA[j & 3], 0, 0, 0);
      cB[j & 3] = __builtin_amdgcn_mfma_f32_16x16x32_bf16(a, bfB[kt], cB[j & 3], 0, 0, 0);
    }

    // ---- 16-step block boundary: batched HBM traffic
    if (tb == 0) {
#pragma unroll
      for (int i = 0; i < 16; ++i) xbuf[w][i][xrow][xcol] = xreg[i];
      if (t && prod) {                    // flush steps [t-16, t)
        const int tf = t - 16;
        for (int u = 0; u < 16; ++u) {
          rnn[((long)r0 * T + (tf + u)) * HID + cca]       = rstage[u][0][w * 32 + lm];
          rnn[((long)(r0 + 1) * T + (tf + u)) * HID + cca] = rstage[u][1][w * 32 + lm];
          rnn[((long)r0 * T + (tf + u)) * HID + ccb]       = rstage[u][0][w * 32 + lm + 16];
          rnn[((long)(r0 + 1) * T + (tf + u)) * HID + ccb] = rstage[u][1][w * 32 + lm + 16];
        }
      }
#pragma unroll
      for (int i = 0; i < 16; ++i) {      // issue next block's xp loads
        const int tt = t + 16 + i;
        if (tt < T)
          xreg[i] = rnn[((long)(r0 + xrow) * T + tt) * HID + n_base + xcol];
      }
    }

    // ---- epilogue
    if (prod) {  // C layout: col = lane&15, row = (lane>>4)*4 + reg
      const float xa0 = xbuf[w][tb][0][lm];
      const float xa1 = xbuf[w][tb][1][lm];
      const float xb0 = xbuf[w][tb][0][lm + 16];
      const float xb1 = xbuf[w][tb][1][lm + 16];
      const float za0 = (cA[0][0] + cA[1][0]) + (cA[2][0] + cA[3][0]) + xa0;
      const float za1 = (cA[0][1] + cA[1][1]) + (cA[2][1] + cA[3][1]) + xa1;
      const float zb0 = (cB[0][0] + cB[1][0]) + (cB[2][0] + cB[3][0]) + xb0;
      const float zb1 = (cB[0][1] + cB[1][1]) + (cB[2][1] + cB[3][1]) + xb1;
      const float ha0 = 1.f / (1.f + __expf(-za0));
      const float ha1 = 1.f / (1.f + __expf(-za1));
      const float hb0 = 1.f / (1.f + __expf(-zb0));
      const float hb1 = 1.f / (1.f + __expf(-zb1));
      __hip_bfloat16 ba0 = __float2bfloat16(ha0);
      __hip_bfloat16 ba1 = __float2bfloat16(ha1);
      __hip_bfloat16 bb0 = __float2bfloat16(hb0);
      __hip_bfloat16 bb1 = __float2bfloat16(hb1);
      const unsigned short ua0 = *reinterpret_cast<unsigned short*>(&ba0);
      const unsigned short ua1 = *reinterpret_cast<unsigned short*>(&ba1);
      const unsigned short ub0 = *reinterpret_cast<unsigned short*>(&bb0);
      const unsigned short ub1 = *reinterpret_cast<unsigned short*>(&bb1);

      const uint32_t tag = (uint32_t)(t + 1) & 0xFFFFu;
      const uint64_t worda =
          (uint64_t)(((uint32_t)ua0 << 16) | tag) |
          ((uint64_t)(((uint32_t)ua1 << 16) | tag) << 32);
      const uint64_t wordb =
          (uint64_t)(((uint32_t)ub0 << 16) | tag) |
          ((uint64_t)(((uint32_t)ub1 << 16) | tag) << 32);
      const size_t dbase = (size_t)(t & 1) * NGROUP * HID + exbase;
      l2_store64(h_fast + dbase + cca, worda);    // same-XCD L2 (fast)
      l2_store64(h_fast + dbase + ccb, wordb);
      __hip_atomic_store(h_safe + dbase + cca, worda, __ATOMIC_RELAXED,
                         __HIP_MEMORY_SCOPE_AGENT);  // MALL (fallback net)
      __hip_atomic_store(h_safe + dbase + ccb, wordb, __ATOMIC_RELAXED,
                         __HIP_MEMORY_SCOPE_AGENT);

      // own-slice bypass: stage h_t for our own next Phase A
      hl[t & 1][0][cca] = ua0;
      hl[t & 1][1][cca] = ua1;
      hl[t & 1][0][ccb] = ub0;
      hl[t & 1][1][ccb] = ub1;

      // stage f32 outputs (flushed at block boundary)
      rstage[tb][0][w * 32 + lm]      = ha0;
      rstage[tb][1][w * 32 + lm]      = ha1;
      rstage[tb][0][w * 32 + lm + 16] = hb0;
      rstage[tb][1][w * 32 + lm + 16] = hb1;
      if (t == T - 1) {
        hn_out[r0 * HID + cca]       = ha0;
        hn_out[(r0 + 1) * HID + cca] = ha1;
        hn_out[r0 * HID + ccb]       = hb0;
        hn_out[(r0 + 1) * HID + ccb] = hb1;
      }
    }
    __syncthreads();                      // epilogue hl visible for t+1
  }

  // ---- post-loop flush of the final partial block
  if (prod) {
    const int tf = (T - 1) & ~15;
    for (int u = 0; u < T - tf; ++u) {
      rnn[((long)r0 * T + (tf + u)) * HID + cca]       = rstage[u][0][w * 32 + lm];
      rnn[((long)(r0 + 1) * T + (tf + u)) * HID + cca] = rstage[u][1][w * 32 + lm];
      rnn[((long)r0 * T + (tf + u)) * HID + ccb]       = rstage[u][0][w * 32 + lm + 16];
      rnn[((long)(r0 + 1) * T + (tf + u)) * HID + ccb] = rstage[u][1][w * 32 + lm + 16];
    }
  }
}

// ---------------------------------------------------------------------------
// K3: out[b,t,:] = sigmoid(rnn[b,t,:] @ W_fc + b_fc)
// ---------------------------------------------------------------------------
__global__ __launch_bounds__(256) void fc_kernel(
    const float* __restrict__ rnn, const float* __restrict__ W_fc,
    const float* __restrict__ b_fc, float* __restrict__ out) {
  const int lane = threadIdx.x & 63;
  const int wid  = threadIdx.x >> 6;
  const long row = (long)blockIdx.x * 4 + wid;

  const float4* __restrict__ hrow = (const float4*)(rnn + row * HID);
  const float4* __restrict__ Wfc4 = (const float4*)W_fc;

  float a0 = 0.f, a1 = 0.f;
#pragma unroll
  for (int u = 0; u < 2; ++u) {
    const float4 hv = hrow[lane * 2 + u];
    const int j0 = lane * 8 + u * 4;
    const float4 wA = Wfc4[(j0 >> 1)];
    const float4 wB = Wfc4[(j0 >> 1) + 1];
    a0 += hv.x * wA.x + hv.y * wA.z + hv.z * wB.x + hv.w * wB.z;
    a1 += hv.x * wA.y + hv.y * wA.w + hv.z * wB.y + hv.w * wB.w;
  }
#pragma unroll
  for (int off = 32; off > 0; off >>= 1) {
    a0 += __shfl_down(a0, off, 64);
    a1 += __shfl_down(a1, off, 64);
  }
  if (lane == 0) {
    out[row * 2 + 0] = 1.f / (1.f + __expf(-(a0 + b_fc[0])));
    out[row * 2 + 1] = 1.f / (1.f + __expf(-(a1 + b_fc[1])));
  }
}

// ---------------------------------------------------------------------------
extern "C" void kernel_launch(void* const* d_in, const int* in_sizes, int n_in,
                              void* d_out, int out_size, void* d_ws,
                              size_t ws_size, hipStream_t stream) {
  const float* inp  = (const float*)d_in[0];
  const float* hn   = (const float*)d_in[1];
  const float* W_hh = (const float*)d_in[2];
  const float* W_ih = (const float*)d_in[3];
  const float* W_fc = (const float*)d_in[4];
  const float* b_fc = (const float*)d_in[5];

  float* out    = (float*)d_out;              // [B,T,ACT]
  float* hn_out = out + (long)B * T * ACT;    // [1,B,HID]
  float* rnn    = hn_out + (long)B * HID;     // [B,T,HID]

  // workspace: ctrl (256 B) | h_fast[2][NGROUP][HID] u64 (256 KB) | h_safe
  uint32_t* ctrl   = (uint32_t*)d_ws;
  uint64_t* h_fast = (uint64_t*)((char*)d_ws + 256);
  const size_t HCNT = (size_t)2 * NGROUP * HID;             // u64 words
  uint64_t* h_safe =
      (ws_size >= 256 + 2 * HCNT * sizeof(uint64_t)) ? (h_fast + HCNT)
                                                     : h_fast;  // alias-safe

  hipLaunchKernelGGL(init_kernel, dim3((NGROUP * HID) / 256), dim3(256), 0,
                     stream, hn, h_fast, h_safe, ctrl);
  hipLaunchKernelGGL(xproj_kernel, dim3((B * T) / 16), dim3(256), 0, stream,
                     inp, W_ih, rnn);
  hipLaunchKernelGGL(rnn_mfma, dim3(NLAUNCH), dim3(512), 0, stream,
                     W_hh, rnn, hn_out, h_fast, h_safe, ctrl);
  hipLaunchKernelGGL(fc_kernel, dim3((B * T) / 4), dim3(256), 0, stream,
                     rnn, W_fc, b_fc, out);
}

// Round 9
// 1967.858 us; speedup vs baseline: 4.1365x; 4.1365x over previous
//
#include <hip/hip_runtime.h>
#include <hip/hip_bf16.h>
#include <stdint.h>
#include <math.h>

#define B   64
#define T   1000
#define INP 64
#define HID 512
#define ACT 2

#define NSLICE 4                    // column slices per row-group
#define MROWS  2                    // batch rows per block
#define NGROUP (B / MROWS)          // 32 row-groups
#define NBLOCKS (NGROUP * NSLICE)   // 128 worker slots
#define NLAUNCH 256                 // launched blocks (claim surplus exits)
#define WORK_PER_XCD 16             // 4 groups x 4 slices per XCD
#define COLS   (HID / NSLICE)       // 128 cols per block
#define HLPAD  544                  // row stride (shorts): bank shift 16/row

#define FAST_GUARD 512              // fast-poll budget (sticky demotion)
#define SAFE_GUARD (1 << 18)        // MALL-poll budget (fail fast, no hang)

typedef __attribute__((ext_vector_type(8))) short short8;     // 8 bf16
typedef __attribute__((ext_vector_type(4))) float floatx4;    // MFMA C/D

// ---------------------------------------------------------------------------
// Role split rationale: vmcnt is PER-WAVE and retires IN ORDER, so a wave
// that both polls and stores pays its slowest store ack (~700-900cy MALL/HBM)
// on every poll wait. Waves 0-3: compute + tagged publication (h_fast L2 +
// h_safe MALL — TIMELY, from the value-producing wave; R8 lesson: lagging
// h_safe across a barrier deadlocks mutually-demoted partners). Waves 4-5:
// poll ONLY (no stores -> clean vmcnt). Waves 6-7: rnn/xp HBM traffic only.
// ---------------------------------------------------------------------------
__device__ __forceinline__ void l2_store64(uint64_t* p, uint64_t v) {
  asm volatile("global_store_dwordx2 %0, %1, off"
               :: "v"(p), "v"(v) : "memory");
}
__device__ __forceinline__ int get_xcc_id() {
  int x;
  asm volatile("s_getreg_b32 %0, hwreg(HW_REG_XCC_ID)" : "=s"(x));
  return x & 7;
}
__device__ __forceinline__ int tag_ok64(uint64_t v, uint64_t want64) {
  return ((v ^ want64) & 0x0000FFFF0000FFFFull) == 0;
}

// ctrl layout (u32): [0..7] per-XCD claim counters, [8] claimed, [9] arrivals,
// [10] mode flag (0=undecided, 1=fallback layout, 2=XCD layout)
#define CTRL_WORDS 16

// ---------------------------------------------------------------------------
// Exchange word: [parity][group][col] -> u64 = (row1<<32)|row0, each u32 =
// (bf16 bits << 16) | (step_tag & 0xFFFF); h_t carries tag t+1.
// ---------------------------------------------------------------------------
__global__ __launch_bounds__(256) void init_kernel(
    const float* __restrict__ hn, uint64_t* __restrict__ h_fast,
    uint64_t* __restrict__ h_safe, uint32_t* __restrict__ ctrl) {
  if (blockIdx.x == 0 && threadIdx.x < CTRL_WORDS) ctrl[threadIdx.x] = 0;
  const int i   = blockIdx.x * 256 + threadIdx.x;  // 0 .. NGROUP*HID-1
  const int g   = i >> 9;
  const int col = i & (HID - 1);
  __hip_bfloat16 b0 = __float2bfloat16(hn[(2 * g) * HID + col]);
  __hip_bfloat16 b1 = __float2bfloat16(hn[(2 * g + 1) * HID + col]);
  const uint32_t w0 = ((uint32_t)*reinterpret_cast<unsigned short*>(&b0)) << 16;
  const uint32_t w1 = ((uint32_t)*reinterpret_cast<unsigned short*>(&b1)) << 16;
  const uint64_t v  = (uint64_t)w0 | ((uint64_t)w1 << 32);  // tag 0
  const size_t p1 = (size_t)NGROUP * HID + i;               // parity 1
  h_fast[p1] = v;
  h_safe[p1] = v;
  h_fast[i] = 0x0000FFFE0000FFFEull;  // parity 0: non-matching tag
  h_safe[i] = 0x0000FFFE0000FFFEull;
}

// ---------------------------------------------------------------------------
// K1: xproj[b,t,:] = inp[b,t,:] @ W_ih  -> rnn slab (overwritten by h later)
// ---------------------------------------------------------------------------
__global__ __launch_bounds__(256) void xproj_kernel(
    const float* __restrict__ inp, const float* __restrict__ W_ih,
    float* __restrict__ rnn) {
  __shared__ float xin[16 * INP];
  const int tid = threadIdx.x;
  const long r0 = (long)blockIdx.x * 16;

  const float4* inp4 = (const float4*)(inp + r0 * INP);
  ((float4*)xin)[tid] = inp4[tid];
  __syncthreads();

  const int j = tid, j2 = tid + 256;
  float acc0[16], acc1[16];
#pragma unroll
  for (int r = 0; r < 16; ++r) { acc0[r] = 0.f; acc1[r] = 0.f; }

  for (int i = 0; i < INP; ++i) {
    const float w0 = W_ih[i * HID + j];
    const float w1 = W_ih[i * HID + j2];
#pragma unroll
    for (int r = 0; r < 16; ++r) {
      const float x = xin[r * INP + i];
      acc0[r] = fmaf(x, w0, acc0[r]);
      acc1[r] = fmaf(x, w1, acc1[r]);
    }
  }
#pragma unroll
  for (int r = 0; r < 16; ++r) {
    rnn[(r0 + r) * HID + j]  = acc0[r];
    rnn[(r0 + r) * HID + j2] = acc1[r];
  }
}

// ---------------------------------------------------------------------------
// K2: recurrence with wave-role specialization.
// ---------------------------------------------------------------------------
__global__ __launch_bounds__(512, 2) void rnn_mfma(
    const float* __restrict__ W_hh, float* __restrict__ rnn,
    float* __restrict__ hn_out, const float* __restrict__ hn,
    uint64_t* __restrict__ h_fast, uint64_t* __restrict__ h_safe,
    uint32_t* __restrict__ ctrl) {
  __shared__ __align__(16) unsigned short hl[2][MROWS][HLPAD];
  __shared__ float rstage[2][MROWS][COLS];  // f32 h, parity dbuf (exact rnn)
  __shared__ float xpbuf[2][MROWS][COLS];   // f32 xproj, parity dbuf
  __shared__ int sh_g, sh_s, sh_work, sh_mode;

  const int tid = threadIdx.x;

  // ---- claim a (group, slice) slot on this block's physical XCD
  if (tid == 0) {
    uint32_t* cnt      = ctrl;
    uint32_t* claimed  = ctrl + 8;
    uint32_t* arrivals = ctrl + 9;
    uint32_t* flag     = ctrl + 10;
    const int xcc = get_xcc_id();
    const int slot = (int)__hip_atomic_fetch_add(
        &cnt[xcc], 1u, __ATOMIC_RELAXED, __HIP_MEMORY_SCOPE_AGENT);
    int work = 0, g = 0, s = 0;
    if (slot < WORK_PER_XCD) {          // groups [4*xcc,4*xcc+4) x 4 slices
      g = xcc * 4 + (slot >> 2);
      s = slot & 3;
      work = 1;
      __hip_atomic_fetch_add(claimed, 1u, __ATOMIC_RELEASE,
                             __HIP_MEMORY_SCOPE_AGENT);
    }
    const int arr = (int)__hip_atomic_fetch_add(
        arrivals, 1u, __ATOMIC_ACQ_REL, __HIP_MEMORY_SCOPE_AGENT);
    if (arr == NLAUNCH - 1) {
      const uint32_t c = __hip_atomic_load(claimed, __ATOMIC_ACQUIRE,
                                           __HIP_MEMORY_SCOPE_AGENT);
      __hip_atomic_store(flag, (c == NBLOCKS) ? 2u : 1u, __ATOMIC_RELEASE,
                         __HIP_MEMORY_SCOPE_AGENT);
    }
    uint32_t f = 0; int guard = 0;
    do {
      f = __hip_atomic_load(flag, __ATOMIC_ACQUIRE, __HIP_MEMORY_SCOPE_AGENT);
    } while (f == 0 && ++guard < (1 << 20));
    if (f != 2) {                       // globally-consistent fallback layout
      work = (blockIdx.x < NBLOCKS);
      g = blockIdx.x & (NGROUP - 1);
      s = blockIdx.x >> 5;
    }
    sh_g = g; sh_s = s; sh_work = work; sh_mode = (f == 2);
  }
  __syncthreads();
  if (!sh_work) return;

  const int g = __builtin_amdgcn_readfirstlane(sh_g);
  const int s = __builtin_amdgcn_readfirstlane(sh_s);
  const int fast2 = __builtin_amdgcn_readfirstlane(sh_mode);

  const int lane = tid & 63;
  const int w    = tid >> 6;            // wave 0..7
  const int r0   = g * MROWS;
  const int lm   = lane & 15;
  const int lq   = lane >> 4;

  const bool compw = (w < 4);
  const bool pollw = (w == 4 || w == 5);
  const bool storew = (w >= 6);

  // ---- prestage t=0: h_{-1} from hn (no exchange), xp(0) from rnn slab
  {
    __hip_bfloat16 a0 = __float2bfloat16(hn[r0 * HID + tid]);
    __hip_bfloat16 a1 = __float2bfloat16(hn[(r0 + 1) * HID + tid]);
    hl[1][0][tid] = *reinterpret_cast<unsigned short*>(&a0);
    hl[1][1][tid] = *reinterpret_cast<unsigned short*>(&a1);
    if (tid < 2 * COLS) {
      const int row = tid >> 7, L = tid & (COLS - 1);
      xpbuf[0][row][L] = rnn[((long)(r0 + row) * T) * HID + s * COLS + L];
    }
  }

  // ---- compute-wave setup: W_hh B-frags (2 n-tiles x 16 k-chunks)
  short8 bfA[16], bfB[16];
  int cca = 0, ccb = 0;
  if (compw) {
    cca = s * COLS + w * 32 + lm;
    ccb = cca + 16;
#pragma unroll
    for (int kt = 0; kt < 16; ++kt) {
      short8 fa, fb;
#pragma unroll
      for (int i = 0; i < 8; ++i) {
        const int k = kt * 32 + lq * 8 + i;
        __hip_bfloat16 ha = __float2bfloat16(W_hh[k * HID + cca]);
        __hip_bfloat16 hb = __float2bfloat16(W_hh[k * HID + ccb]);
        fa[i] = *reinterpret_cast<short*>(&ha);
        fb[i] = *reinterpret_cast<short*>(&hb);
      }
      bfA[kt] = fa;
      bfB[kt] = fb;
    }
  }

  // ---- poll-wave setup: 3 remote u64 words per lane (384 total)
  int c0 = 0, c1 = 0, c2 = 0;
  if (pollw) {
    const int L = (w - 4) * 64 + lane;  // 0..127
    const int j0 = 3 * L;
    c0 = (j0 + 0 < s * COLS) ? (j0 + 0) : (j0 + 0 + COLS);
    c1 = (j0 + 1 < s * COLS) ? (j0 + 1) : (j0 + 1 + COLS);
    c2 = (j0 + 2 < s * COLS) ? (j0 + 2) : (j0 + 2 + COLS);
  }
  int fastmode = fast2;                 // sticky per wave (poll waves)

  const int arow = lm & 1;
  const bool prod = (lq == 0);

  for (int t = 0; t < T; ++t) {
    const int p = (t + 1) & 1;          // parity holding h_{t-1}

    // ---- poll waves: fetch remote 384 cols of h_{t-1} (clean vmcnt)
    if (pollw && t > 0) {
      const uint64_t want64 =
          (uint64_t)(t & 0xFFFF) * 0x0000000100000001ull;
      const size_t base = ((size_t)p * NGROUP + g) * HID;
      const uint64_t *p0 = h_fast + base + c0, *p1 = h_fast + base + c1,
                     *p2 = h_fast + base + c2;
      uint64_t va = 0, vb = 0, vc = 0;
      if (fastmode) {
        int it = 0;
        for (;;) {
          asm volatile(
              "global_load_dwordx2 %0, %3, off sc0\n\t"
              "global_load_dwordx2 %1, %4, off sc0\n\t"
              "global_load_dwordx2 %2, %5, off sc0\n\t"
              "s_waitcnt vmcnt(0)"
              : "=&v"(va), "=&v"(vb), "=&v"(vc)
              : "v"(p0), "v"(p1), "v"(p2) : "memory");
          const int ok = tag_ok64(va, want64) & tag_ok64(vb, want64) &
                         tag_ok64(vc, want64);
          if (__all(ok)) break;
          if (++it > FAST_GUARD) { fastmode = 0; break; }
        }
      }
      if (!fastmode) {                  // MALL path (demoted or fallback)
        const uint64_t *q0 = h_safe + base + c0, *q1 = h_safe + base + c1,
                       *q2 = h_safe + base + c2;
        int gd = 0;
        for (;;) {
          va = __hip_atomic_load(q0, __ATOMIC_RELAXED,
                                 __HIP_MEMORY_SCOPE_AGENT);
          vb = __hip_atomic_load(q1, __ATOMIC_RELAXED,
                                 __HIP_MEMORY_SCOPE_AGENT);
          vc = __hip_atomic_load(q2, __ATOMIC_RELAXED,
                                 __HIP_MEMORY_SCOPE_AGENT);
          const int ok = tag_ok64(va, want64) & tag_ok64(vb, want64) &
                         tag_ok64(vc, want64);
          if (__all(ok)) break;
          if (++gd > SAFE_GUARD) break;
        }
      }
      hl[p][0][c0] = (unsigned short)((uint32_t)va >> 16);
      hl[p][1][c0] = (unsigned short)((uint32_t)(va >> 32) >> 16);
      hl[p][0][c1] = (unsigned short)((uint32_t)vb >> 16);
      hl[p][1][c1] = (unsigned short)((uint32_t)(vb >> 32) >> 16);
      hl[p][0][c2] = (unsigned short)((uint32_t)vc >> 16);
      hl[p][1][c2] = (unsigned short)((uint32_t)(vc >> 32) >> 16);
    }
    __syncthreads();                    // hl[p] complete; prior-phase LDS ok

    if (compw) {
      // ---- 32 MFMA (2 tiles x 16 k), A-frag shared across tiles
      floatx4 cAc[4], cBc[4];
#pragma unroll
      for (int j = 0; j < 4; ++j) {
        cAc[j] = floatx4{0.f, 0.f, 0.f, 0.f};
        cBc[j] = floatx4{0.f, 0.f, 0.f, 0.f};
      }
#pragma unroll
      for (int kt = 0; kt < 16; ++kt) {
        short8 a = *(const short8*)(&hl[p][arow][kt * 32 + lq * 8]);
        cAc[kt & 3] = __builtin_amdgcn_mfma_f32_16x16x32_bf16(a, bfA[kt], cAc[kt & 3], 0, 0, 0);
        cBc[kt & 3] = __builtin_amdgcn_mfma_f32_16x16x32_bf16(a, bfB[kt], cBc[kt & 3], 0, 0, 0);
      }
      if (prod) {  // C layout: col = lane&15, row = (lane>>4)*4 + reg
        const int Lc = w * 32 + lm;
        const float xa0 = xpbuf[t & 1][0][Lc];
        const float xa1 = xpbuf[t & 1][1][Lc];
        const float xb0 = xpbuf[t & 1][0][Lc + 16];
        const float xb1 = xpbuf[t & 1][1][Lc + 16];
        const float za0 = (cAc[0][0] + cAc[1][0]) + (cAc[2][0] + cAc[3][0]) + xa0;
        const float za1 = (cAc[0][1] + cAc[1][1]) + (cAc[2][1] + cAc[3][1]) + xa1;
        const float zb0 = (cBc[0][0] + cBc[1][0]) + (cBc[2][0] + cBc[3][0]) + xb0;
        const float zb1 = (cBc[0][1] + cBc[1][1]) + (cBc[2][1] + cBc[3][1]) + xb1;
        const float ha0 = 1.f / (1.f + __expf(-za0));
        const float ha1 = 1.f / (1.f + __expf(-za1));
        const float hb0 = 1.f / (1.f + __expf(-zb0));
        const float hb1 = 1.f / (1.f + __expf(-zb1));
        __hip_bfloat16 ba0 = __float2bfloat16(ha0);
        __hip_bfloat16 ba1 = __float2bfloat16(ha1);
        __hip_bfloat16 bb0 = __float2bfloat16(hb0);
        __hip_bfloat16 bb1 = __float2bfloat16(hb1);
        const unsigned short ua0 = *reinterpret_cast<unsigned short*>(&ba0);
        const unsigned short ua1 = *reinterpret_cast<unsigned short*>(&ba1);
        const unsigned short ub0 = *reinterpret_cast<unsigned short*>(&bb0);
        const unsigned short ub1 = *reinterpret_cast<unsigned short*>(&bb1);

        // critical path: tagged publication, TIMELY on both tiers
        const uint32_t tag = (uint32_t)(t + 1) & 0xFFFFu;
        const uint64_t worda =
            (uint64_t)(((uint32_t)ua0 << 16) | tag) |
            ((uint64_t)(((uint32_t)ua1 << 16) | tag) << 32);
        const uint64_t wordb =
            (uint64_t)(((uint32_t)ub0 << 16) | tag) |
            ((uint64_t)(((uint32_t)ub1 << 16) | tag) << 32);
        const size_t dbase = ((size_t)(t & 1) * NGROUP + g) * HID;
        l2_store64(h_fast + dbase + cca, worda);
        l2_store64(h_fast + dbase + ccb, wordb);
        __hip_atomic_store(h_safe + dbase + cca, worda, __ATOMIC_RELAXED,
                           __HIP_MEMORY_SCOPE_AGENT);
        __hip_atomic_store(h_safe + dbase + ccb, wordb, __ATOMIC_RELAXED,
                           __HIP_MEMORY_SCOPE_AGENT);

        // own-slice LDS bypass + f32 stage for the flush waves
        hl[t & 1][0][cca] = ua0;
        hl[t & 1][1][cca] = ua1;
        hl[t & 1][0][ccb] = ub0;
        hl[t & 1][1][ccb] = ub1;
        rstage[t & 1][0][Lc]      = ha0;
        rstage[t & 1][1][Lc]      = ha1;
        rstage[t & 1][0][Lc + 16] = hb0;
        rstage[t & 1][1][Lc + 16] = hb1;
        if (t == T - 1) {
          hn_out[r0 * HID + cca]       = ha0;
          hn_out[(r0 + 1) * HID + cca] = ha1;
          hn_out[r0 * HID + ccb]       = hb0;
          hn_out[(r0 + 1) * HID + ccb] = hb1;
        }
      }
    } else if (storew) {
      const int L = (w - 6) * 64 + lane;      // 0..127
      const int c = s * COLS + L;             // absolute column
      if (t > 0) {                      // exact f32 h_{t-1} -> rnn slab
        rnn[((long)r0 * T + (t - 1)) * HID + c]       = rstage[p][0][L];
        rnn[((long)(r0 + 1) * T + (t - 1)) * HID + c] = rstage[p][1][L];
      }
      if (t + 1 < T) {                  // prefetch xp(t+1) into LDS
        xpbuf[(t + 1) & 1][0][L] =
            rnn[((long)r0 * T + (t + 1)) * HID + c];
        xpbuf[(t + 1) & 1][1][L] =
            rnn[((long)(r0 + 1) * T + (t + 1)) * HID + c];
      }
    }
    // poll waves: nothing post-barrier; loop to next step's poll
  }

  // ---- post-loop: flush h_{T-1} (barrier: rstage written by compute waves)
  __syncthreads();
  if (storew) {
    const int L = (w - 6) * 64 + lane;
    const int c = s * COLS + L;
    const int pf = (T - 1) & 1;
    rnn[((long)r0 * T + (T - 1)) * HID + c]       = rstage[pf][0][L];
    rnn[((long)(r0 + 1) * T + (T - 1)) * HID + c] = rstage[pf][1][L];
  }
}

// ---------------------------------------------------------------------------
// K3: out[b,t,:] = sigmoid(rnn[b,t,:] @ W_fc + b_fc)
// ---------------------------------------------------------------------------
__global__ __launch_bounds__(256) void fc_kernel(
    const float* __restrict__ rnn, const float* __restrict__ W_fc,
    const float* __restrict__ b_fc, float* __restrict__ out) {
  const int lane = threadIdx.x & 63;
  const int wid  = threadIdx.x >> 6;
  const long row = (long)blockIdx.x * 4 + wid;

  const float4* __restrict__ hrow = (const float4*)(rnn + row * HID);
  const float4* __restrict__ Wfc4 = (const float4*)W_fc;

  float a0 = 0.f, a1 = 0.f;
#pragma unroll
  for (int u = 0; u < 2; ++u) {
    const float4 hv = hrow[lane * 2 + u];
    const int j0 = lane * 8 + u * 4;
    const float4 wA = Wfc4[(j0 >> 1)];
    const float4 wB = Wfc4[(j0 >> 1) + 1];
    a0 += hv.x * wA.x + hv.y * wA.z + hv.z * wB.x + hv.w * wB.z;
    a1 += hv.x * wA.y + hv.y * wA.w + hv.z * wB.y + hv.w * wB.w;
  }
#pragma unroll
  for (int off = 32; off > 0; off >>= 1) {
    a0 += __shfl_down(a0, off, 64);
    a1 += __shfl_down(a1, off, 64);
  }
  if (lane == 0) {
    out[row * 2 + 0] = 1.f / (1.f + __expf(-(a0 + b_fc[0])));
    out[row * 2 + 1] = 1.f / (1.f + __expf(-(a1 + b_fc[1])));
  }
}

// ---------------------------------------------------------------------------
extern "C" void kernel_launch(void* const* d_in, const int* in_sizes, int n_in,
                              void* d_out, int out_size, void* d_ws,
                              size_t ws_size, hipStream_t stream) {
  const float* inp  = (const float*)d_in[0];
  const float* hn   = (const float*)d_in[1];
  const float* W_hh = (const float*)d_in[2];
  const float* W_ih = (const float*)d_in[3];
  const float* W_fc = (const float*)d_in[4];
  const float* b_fc = (const float*)d_in[5];

  float* out    = (float*)d_out;              // [B,T,ACT]
  float* hn_out = out + (long)B * T * ACT;    // [1,B,HID]
  float* rnn    = hn_out + (long)B * HID;     // [B,T,HID]

  // workspace: ctrl (256 B) | h_fast[2][NGROUP][HID] u64 (256 KB) | h_safe
  uint32_t* ctrl   = (uint32_t*)d_ws;
  uint64_t* h_fast = (uint64_t*)((char*)d_ws + 256);
  const size_t HCNT = (size_t)2 * NGROUP * HID;
  uint64_t* h_safe =
      (ws_size >= 256 + 2 * HCNT * sizeof(uint64_t)) ? (h_fast + HCNT)
                                                     : h_fast;  // alias-safe

  hipLaunchKernelGGL(init_kernel, dim3((NGROUP * HID) / 256), dim3(256), 0,
                     stream, hn, h_fast, h_safe, ctrl);
  hipLaunchKernelGGL(xproj_kernel, dim3((B * T) / 16), dim3(256), 0, stream,
                     inp, W_ih, rnn);
  hipLaunchKernelGGL(rnn_mfma, dim3(NLAUNCH), dim3(512), 0, stream,
                     W_hh, rnn, hn_out, hn, h_fast, h_safe, ctrl);
  hipLaunchKernelGGL(fc_kernel, dim3((B * T) / 4), dim3(256), 0, stream,
                     rnn, W_fc, b_fc, out);
}